// Round 4
// baseline (113.663 us; speedup 1.0000x reference)
//
#include <hip/hip_runtime.h>

#define NBLK 32
#define TPB  256

__device__ __forceinline__ float relu_(float x) { return fmaxf(x, 0.f); }

// 2-step speculative grid-sync, with SELF-VALIDATING publish atoms:
//  each published float is one aligned u64: lo32 = tag (g+1, monotone 1..4),
//  hi32 = float bits. An 8-B atomic load can't tear, so tag fresh => payload
//  fresh; the poll loop IS the fan-in (one LLC round trip per sync, not two).
//  Poison 0xAA..AA gives lo32=0xAAAAAAAA != 1..4 -> no init kernel needed.
//  pub layout: u64 pub[(g*NBLK + b)*64 + j], j<42 (group slots 256B-strided).

__launch_bounds__(TPB, 1)
__global__ void actor_kernel(
    const float* __restrict__ inp,
    const float* __restrict__ conv_w, const float* __restrict__ conv_b,
    const float* __restrict__ w0, const float* __restrict__ b0,
    const float* __restrict__ w1, const float* __restrict__ b1,
    const float* __restrict__ w2, const float* __restrict__ b2,
    const float* __restrict__ w3, const float* __restrict__ b3,
    const float* __restrict__ w4, const float* __restrict__ b4,
    float* __restrict__ out, unsigned long long* __restrict__ pub)
{
    const int tid = threadIdx.x;
    const int b   = blockIdx.x;

    __shared__ __align__(16) float lw3[4 * 2048];    // 32 KB row slice
    __shared__ __align__(16) float lfeat[2048];
    __shared__ __align__(16) float lc2[512], lc3[512]; // next-step common conv feats
    __shared__ float lbase2[128], lbase3[128], ls5[128];
    __shared__ float ls0[6 * 128];                   // 6 s0 variants (constant)
    __shared__ float ltmp[512];                      // s1c (128) + s4c (384), constant
    __shared__ __align__(16) float lcw[512];
    __shared__ float lcb[128];
    __shared__ float lw0v[128], lb0v[128], lw1v[128], lb1v[128];
    __shared__ float lw2v[128], lb2v[128], lb3v[128];
    __shared__ float lw4[768], lb4v[8];
    __shared__ float st2[8], st3[8], st4[8];
    __shared__ float sx[8];     // 0:st[0,7] 1:st[1,7] 2:st[4,7] 3:st[4,0] 4:vs
    __shared__ float lbw[8];
    __shared__ float h_lds[4], hv_lds[4 * 8];
    __shared__ float s_red[192];                     // fan-in partial sums
    __shared__ float red[48];

    // ---- one-time staging ----
    {
        const float4* g4 = (const float4*)(w3 + b * 4 * 2048);
        float4* l4 = (float4*)lw3;
        for (int idx = tid; idx < 2048; idx += TPB) l4[idx] = g4[idx];
    }
    for (int idx = tid; idx < 512; idx += TPB) lcw[idx] = conv_w[idx];
    if (tid < 128) {
        lcb[tid]  = conv_b[tid];
        lw0v[tid] = w0[tid]; lb0v[tid] = b0[tid];
        lw1v[tid] = w1[tid]; lb1v[tid] = b1[tid];
        lw2v[tid] = w2[tid]; lb2v[tid] = b2[tid];
        lb3v[tid] = b3[tid];
    }
    for (int idx = tid; idx < 768; idx += TPB) lw4[idx] = w4[idx];
    if (tid < 6) lb4v[tid] = b4[tid];
    if (tid < 8) {
        st2[tid] = inp[16 + tid];
        st3[tid] = inp[24 + tid];
        st4[tid] = inp[32 + tid];
        lbw[tid] = inp[48 + tid];
    }
    if (tid == 0) {
        sx[0] = inp[7];   sx[1] = inp[15];
        sx[2] = inp[39];  sx[3] = inp[32];
        sx[4] = inp[56];
    }
    __syncthreads();

    // ---- constant-across-steps speculative feats ----
    if (tid < 128) {
        const float vb[6] = {300.f, 750.f, 1200.f, 1850.f, 2850.f, 4300.f};
        #pragma unroll
        for (int v = 0; v < 6; ++v)
            ls0[v * 128 + tid] = relu_(vb[v] * (1.f / 4300.f) * lw0v[tid] + lb0v[tid]);
        ltmp[tid] = relu_(3.0f * lw1v[tid] + lb1v[tid]);       // s1 after any update
    }
    for (int m = tid; m < 384; m += TPB) {                     // s4 after any update
        int c = m / 3, w = m - c * 3;
        float a = lcb[c];
        #pragma unroll
        for (int k = 0; k < 4; ++k)
            a += sx[4] * (float)(1 << (w + k)) * 1e-6f * lcw[c * 4 + k];
        ltmp[128 + m] = relu_(a);
    }
    __syncthreads();

    const int wv = tid >> 6, lane = tid & 63;
    const float* wr = lw3 + wv * 2048;                          // this wave's w3 row
    const float bias3 = lb3v[b * 4 + wv];

    // per-lane constant dot-partials: hs0p[v] (s0 variants), hs14p (s1+s4)
    float hs0p[6], hs14p;
    #pragma unroll
    for (int v = 0; v < 6; ++v)
        hs0p[v] = wr[lane] * ls0[v * 128 + lane] + wr[64 + lane] * ls0[v * 128 + 64 + lane];
    hs14p = wr[128 + lane] * ltmp[lane] + wr[192 + lane] * ltmp[64 + lane];
    #pragma unroll
    for (int k = 0; k < 6; ++k) {
        int m = lane + 64 * k;
        hs14p += wr[1536 + m] * ltmp[128 + m];
    }

    const float VBRc[6] = {300.f, 750.f, 1200.f, 1850.f, 2850.f, 4300.f};

    for (int g = 0; g < 3; ++g) {
        const int i = 2 * g;

        // ---- Phase A: feat_i (exact) + next-step common pieces ----
        if (tid < 128) {
            lfeat[tid]        = relu_(sx[0] * lw0v[tid] + lb0v[tid]);   // s0
            lfeat[1920 + tid] =        sx[2] * lw2v[tid] + lb2v[tid];   // s5 (no relu)
            lbase2[tid] = st2[5] * lcw[tid*4] + st2[6] * lcw[tid*4+1]
                        + st2[7] * lcw[tid*4+2] + lcb[tid];
            lbase3[tid] = st3[5] * lcw[tid*4] + st3[6] * lcw[tid*4+1]
                        + st3[7] * lcw[tid*4+2] + lcb[tid];
            ls5[tid] = sx[3] * lw2v[tid] + lb2v[tid];                   // next s5
        } else {
            int j = tid - 128;
            lfeat[128 + j] = relu_(sx[1] * lw1v[j] + lb1v[j]);          // s1
        }
        for (int m = tid; m < 640; m += TPB) {                          // s2, s3
            int c = m / 5, w = m - c * 5;
            float a2 = lcb[c], a3 = lcb[c];
            #pragma unroll
            for (int k = 0; k < 4; ++k) {
                float cw = lcw[c * 4 + k];
                a2 += st2[w + k] * cw;
                a3 += st3[w + k] * cw;
            }
            lfeat[256 + m] = relu_(a2);
            lfeat[896 + m] = relu_(a3);
        }
        for (int m = tid; m < 384; m += TPB) {                          // s4
            int c = m / 3, w = m - c * 3;
            float a4 = lcb[c];
            #pragma unroll
            for (int k = 0; k < 4; ++k) a4 += st4[w + k] * lcw[c * 4 + k];
            lfeat[1536 + m] = relu_(a4);
        }
        for (int m = tid; m < 512; m += TPB) {       // next-step s2/s3 windows 0..3
            int c = m >> 2, w = m & 3;
            float a2 = lcb[c], a3 = lcb[c];
            #pragma unroll
            for (int k = 0; k < 4; ++k) {
                float cw = lcw[c * 4 + k];
                a2 += st2[w + 1 + k] * cw;
                a3 += st3[w + 1 + k] * cw;
            }
            lc2[m] = relu_(a2);
            lc3[m] = relu_(a3);
        }
        __syncthreads();

        // ---- Phase B: wave dots ----
        float acc_i;
        {
            const float4* w4p = (const float4*)wr;
            const float4* f4p = (const float4*)lfeat;
            float4 acc = make_float4(0.f, 0.f, 0.f, 0.f);
            #pragma unroll
            for (int it = 0; it < 8; ++it) {
                float4 a = w4p[it * 64 + lane];
                float4 f = f4p[it * 64 + lane];
                acc.x += a.x * f.x; acc.y += a.y * f.y;
                acc.z += a.z * f.z; acc.w += a.w * f.w;
            }
            acc_i = (acc.x + acc.y) + (acc.z + acc.w);
        }

        float acc_c = hs14p
                    + wr[1920 + lane] * ls5[lane]
                    + wr[1984 + lane] * ls5[64 + lane];
        #pragma unroll
        for (int k = 0; k < 8; ++k) {
            int m = lane + 64 * k;
            int col = 256 + (m >> 2) * 5 + (m & 3);
            acc_c += wr[col] * lc2[m] + wr[640 + col] * lc3[m];
        }

        float n2[6], n3[6];
        {
            float bwi = lbw[i], vs = sx[4];
            #pragma unroll
            for (int v = 0; v < 6; ++v) {
                float vca   = vs * (float)(1 << v);
                float delay = vca / bwi - 30000.f;
                n2[v] = vca / delay * 1e-3f;
                n3[v] = delay * 1e-4f;
            }
        }
        float accv[6];
        #pragma unroll
        for (int v = 0; v < 6; ++v) accv[v] = hs0p[v];
        #pragma unroll
        for (int t = 0; t < 2; ++t) {
            int c = lane + 64 * t;
            float cw3 = lcw[c * 4 + 3];
            float bb2 = lbase2[c], bb3 = lbase3[c];
            float wc2 = wr[256 + c * 5 + 4], wc3 = wr[896 + c * 5 + 4];
            #pragma unroll
            for (int v = 0; v < 6; ++v)
                accv[v] += relu_(bb2 + n2[v] * cw3) * wc2
                         + relu_(bb3 + n3[v] * cw3) * wc3;
        }

        #pragma unroll
        for (int off = 32; off > 0; off >>= 1) {
            acc_i += __shfl_xor(acc_i, off);
            acc_c += __shfl_xor(acc_c, off);
            #pragma unroll
            for (int v = 0; v < 6; ++v) accv[v] += __shfl_xor(accv[v], off);
        }
        if (lane == 0) {
            h_lds[wv] = relu_(acc_i + bias3);
            #pragma unroll
            for (int v = 0; v < 6; ++v)
                hv_lds[wv * 8 + v] = relu_(acc_c + accv[v] + bias3);
        }
        __syncthreads();

        // ---- Phase C: publish 42 self-validating (tag|payload) atoms ----
        if (tid < 42) {
            int q = tid / 6, t = tid - q * 6;
            float p = 0.f;
            if (q == 0) {
                #pragma unroll
                for (int w = 0; w < 4; ++w) p += lw4[t * 128 + b * 4 + w] * h_lds[w];
            } else {
                #pragma unroll
                for (int w = 0; w < 4; ++w) p += lw4[t * 128 + b * 4 + w] * hv_lds[w * 8 + (q - 1)];
            }
            unsigned long long val =
                ((unsigned long long)__float_as_uint(p) << 32) | (unsigned)(g + 1);
            __hip_atomic_store(&pub[(g * NBLK + b) * 64 + tid], val,
                               __ATOMIC_RELAXED, __HIP_MEMORY_SCOPE_AGENT);
        }

        // ---- Phase D: fused spin+fan-in (one LLC round trip) ----
        if (tid < 168) {
            int j = tid >> 2, part = tid & 3;         // j<42, 8 blocks per part
            const unsigned long long* base = &pub[(g * NBLK + part * 8) * 64 + j];
            unsigned long long v[8];
            #pragma unroll
            for (int k = 0; k < 8; ++k)
                v[k] = __hip_atomic_load(base + k * 64, __ATOMIC_ACQUIRE,
                                         __HIP_MEMORY_SCOPE_AGENT);
            for (;;) {
                bool all = true;
                #pragma unroll
                for (int k = 0; k < 8; ++k)
                    all = all && ((unsigned)v[k] == (unsigned)(g + 1));
                if (all) break;
                __builtin_amdgcn_s_sleep(1);
                #pragma unroll
                for (int k = 0; k < 8; ++k)
                    if ((unsigned)v[k] != (unsigned)(g + 1))
                        v[k] = __hip_atomic_load(base + k * 64, __ATOMIC_ACQUIRE,
                                                 __HIP_MEMORY_SCOPE_AGENT);
            }
            float p = 0.f;
            #pragma unroll
            for (int k = 0; k < 8; ++k)
                p += __uint_as_float((unsigned)(v[k] >> 32));
            s_red[j * 4 + part] = p;
        }
        __syncthreads();
        if (tid < 42)
            red[tid] = lb4v[tid % 6]
                     + ((s_red[tid * 4] + s_red[tid * 4 + 1])
                      + (s_red[tid * 4 + 2] + s_red[tid * 4 + 3]));
        __syncthreads();

        // ---- double argmax + double state update ----
        if (tid == 0) {
            float best = red[0]; int a0 = 0;
            #pragma unroll
            for (int r = 1; r < 6; ++r) if (red[r] > best) { best = red[r]; a0 = r; }
            best = red[6 + 6 * a0]; int a1 = 0;
            #pragma unroll
            for (int r = 1; r < 6; ++r)
                if (red[6 + 6 * a0 + r] > best) { best = red[6 + 6 * a0 + r]; a1 = r; }

            // update(i, a0)
            {
                float vca = sx[4] * (float)(1 << a0);
                float delay = vca / lbw[i] - 30000.f;
                sx[0] = VBRc[a0] * (1.f / 4300.f);
                sx[1] = 3.0f;
                #pragma unroll
                for (int c = 0; c < 7; ++c) { st2[c] = st2[c + 1]; st3[c] = st3[c + 1]; }
                st2[7] = vca / delay * 1e-3f;
                st3[7] = delay * 1e-4f;
                sx[2] = sx[3]; sx[3] = sx[4] * 1e-6f;
                #pragma unroll
                for (int j = 0; j < 6; ++j) st4[j] = sx[4] * (float)(1 << j) * 1e-6f;
            }
            // update(i+1, a1)
            {
                float vca = sx[4] * (float)(1 << a1);
                float delay = vca / lbw[i + 1] - 30000.f;
                sx[0] = VBRc[a1] * (1.f / 4300.f);
                sx[1] = 3.0f;
                #pragma unroll
                for (int c = 0; c < 7; ++c) { st2[c] = st2[c + 1]; st3[c] = st3[c + 1]; }
                st2[7] = vca / delay * 1e-3f;
                st3[7] = delay * 1e-4f;
                sx[2] = sx[3]; sx[3] = sx[4] * 1e-6f;
                #pragma unroll
                for (int j = 0; j < 6; ++j) st4[j] = sx[4] * (float)(1 << j) * 1e-6f;
            }
        }
        __syncthreads();
    }

    // ---- final eval (step 6): full feat only ----
    if (tid < 128) {
        lfeat[tid]        = relu_(sx[0] * lw0v[tid] + lb0v[tid]);
        lfeat[1920 + tid] =        sx[2] * lw2v[tid] + lb2v[tid];
    } else {
        int j = tid - 128;
        lfeat[128 + j] = relu_(sx[1] * lw1v[j] + lb1v[j]);
    }
    for (int m = tid; m < 640; m += TPB) {
        int c = m / 5, w = m - c * 5;
        float a2 = lcb[c], a3 = lcb[c];
        #pragma unroll
        for (int k = 0; k < 4; ++k) {
            float cw = lcw[c * 4 + k];
            a2 += st2[w + k] * cw;
            a3 += st3[w + k] * cw;
        }
        lfeat[256 + m] = relu_(a2);
        lfeat[896 + m] = relu_(a3);
    }
    for (int m = tid; m < 384; m += TPB) {
        int c = m / 3, w = m - c * 3;
        float a4 = lcb[c];
        #pragma unroll
        for (int k = 0; k < 4; ++k) a4 += st4[w + k] * lcw[c * 4 + k];
        lfeat[1536 + m] = relu_(a4);
    }
    __syncthreads();
    {
        const float4* w4p = (const float4*)wr;
        const float4* f4p = (const float4*)lfeat;
        float4 acc = make_float4(0.f, 0.f, 0.f, 0.f);
        #pragma unroll
        for (int it = 0; it < 8; ++it) {
            float4 a = w4p[it * 64 + lane];
            float4 f = f4p[it * 64 + lane];
            acc.x += a.x * f.x; acc.y += a.y * f.y;
            acc.z += a.z * f.z; acc.w += a.w * f.w;
        }
        float s = (acc.x + acc.y) + (acc.z + acc.w);
        #pragma unroll
        for (int off = 32; off > 0; off >>= 1) s += __shfl_xor(s, off);
        if (lane == 0) h_lds[wv] = relu_(s + bias3);
    }
    __syncthreads();
    if (tid < 6) {
        float p = 0.f;
        #pragma unroll
        for (int w = 0; w < 4; ++w) p += lw4[tid * 128 + b * 4 + w] * h_lds[w];
        unsigned long long val =
            ((unsigned long long)__float_as_uint(p) << 32) | 4u;
        __hip_atomic_store(&pub[(3 * NBLK + b) * 64 + tid], val,
                           __ATOMIC_RELAXED, __HIP_MEMORY_SCOPE_AGENT);
    }
    if (b == 0) {
        if (tid < 192) {                           // j = tid>>5 (0..5), bb = tid&31
            int j = tid >> 5, bb = tid & 31;
            unsigned long long v =
                __hip_atomic_load(&pub[(3 * NBLK + bb) * 64 + j],
                                  __ATOMIC_ACQUIRE, __HIP_MEMORY_SCOPE_AGENT);
            while ((unsigned)v != 4u) {
                __builtin_amdgcn_s_sleep(1);
                v = __hip_atomic_load(&pub[(3 * NBLK + bb) * 64 + j],
                                      __ATOMIC_ACQUIRE, __HIP_MEMORY_SCOPE_AGENT);
            }
            s_red[j * 32 + bb] = __uint_as_float((unsigned)(v >> 32));
        }
        __syncthreads();
        if (tid < 6) {
            float p = lb4v[tid];
            #pragma unroll
            for (int bb = 0; bb < NBLK; ++bb) p += s_red[tid * 32 + bb];
            out[tid] = p;
        }
    }
}

extern "C" void kernel_launch(void* const* d_in, const int* in_sizes, int n_in,
                              void* d_out, int out_size, void* d_ws, size_t ws_size,
                              hipStream_t stream) {
    const float* inp    = (const float*)d_in[0];
    const float* conv_w = (const float*)d_in[1];
    const float* conv_b = (const float*)d_in[2];
    const float* w0     = (const float*)d_in[3];
    const float* b0     = (const float*)d_in[4];
    const float* w1     = (const float*)d_in[5];
    const float* b1     = (const float*)d_in[6];
    const float* w2     = (const float*)d_in[7];
    const float* b2     = (const float*)d_in[8];
    const float* w3     = (const float*)d_in[9];
    const float* b3     = (const float*)d_in[10];
    const float* w4     = (const float*)d_in[11];
    const float* b4     = (const float*)d_in[12];

    unsigned long long* pub = (unsigned long long*)d_ws;  // 4*32 slots * 512 B

    actor_kernel<<<NBLK, TPB, 0, stream>>>(inp, conv_w, conv_b,
                                           w0, b0, w1, b1, w2, b2,
                                           w3, b3, w4, b4,
                                           (float*)d_out, pub);
}

// Round 5
// 102.223 us; speedup vs baseline: 1.1119x; 1.1119x over previous
//
#include <hip/hip_runtime.h>

#define NBLK 32
#define TPB  256
#define FSTRIDE 32    // flag spacing in ints (128 B)
#define PSTRIDE 320   // publish slot stride in floats (1280 B)

__device__ __forceinline__ float relu_(float x) { return fmaxf(x, 0.f); }

// 3-sync speculative design (R3 mechanism, R4's fused spin reverted):
//  group 0: steps 0,1   (publish 42: step0 logits + 6 step-1 variants)
//  group 1: steps 2,3   (publish 42)
//  group 2: steps 4,5 + FINAL speculated over (a4,a5): publish 42 + 216.
//  Sync: block b release-stores flags[b*FSTRIDE] = g+1 (monotone 1..3);
//  32 pollers read 32 flags (minimal poll traffic — R4 showed polling storms
//  delay the publisher). Poison 0xAAAAAAAA is negative -> no init kernel.
//  Only block 0 polls sync 3 and writes out; blocks 1..31 publish and exit.

__launch_bounds__(TPB, 1)
__global__ void actor_kernel(
    const float* __restrict__ inp,
    const float* __restrict__ conv_w, const float* __restrict__ conv_b,
    const float* __restrict__ w0, const float* __restrict__ b0,
    const float* __restrict__ w1, const float* __restrict__ b1,
    const float* __restrict__ w2, const float* __restrict__ b2,
    const float* __restrict__ w3, const float* __restrict__ b3,
    const float* __restrict__ w4, const float* __restrict__ b4,
    float* __restrict__ out, int* __restrict__ flags,
    float* __restrict__ partials)
{
    const int tid = threadIdx.x;
    const int b   = blockIdx.x;

    __shared__ __align__(16) float lw3[4 * 2048];    // 32 KB row slice
    __shared__ __align__(16) float lfeat[2048];
    __shared__ __align__(16) float lc2[512], lc3[512]; // next-step common conv feats
    __shared__ float lbase2[128], lbase3[128], ls5[128];
    __shared__ float ls0[6 * 128];                   // 6 s0 variants (constant)
    __shared__ float ltmp[512];                      // s1c (128) + s4c (384), constant
    __shared__ __align__(16) float lcw[512];
    __shared__ float lcb[128];
    __shared__ float lw0v[128], lb0v[128], lw1v[128], lb1v[128];
    __shared__ float lw2v[128], lb2v[128], lb3v[128];
    __shared__ float lw4[768], lb4v[8];
    __shared__ float st2[8], st3[8], st4[8];
    __shared__ float sx[8];     // 0:st[0,7] 1:st[1,7] 2:st[4,7] 3:st[4,0] 4:vs
    __shared__ float lbw[8];
    __shared__ float h_lds[4], hv_lds[4 * 8];
    __shared__ float hf_lds[4 * 40];                 // final h, 36 combos/row
    __shared__ float red[48];
    __shared__ float red2[264];
    __shared__ int   ssel;

    // ---- one-time staging ----
    {
        const float4* g4 = (const float4*)(w3 + b * 4 * 2048);
        float4* l4 = (float4*)lw3;
        for (int idx = tid; idx < 2048; idx += TPB) l4[idx] = g4[idx];
    }
    for (int idx = tid; idx < 512; idx += TPB) lcw[idx] = conv_w[idx];
    if (tid < 128) {
        lcb[tid]  = conv_b[tid];
        lw0v[tid] = w0[tid]; lb0v[tid] = b0[tid];
        lw1v[tid] = w1[tid]; lb1v[tid] = b1[tid];
        lw2v[tid] = w2[tid]; lb2v[tid] = b2[tid];
        lb3v[tid] = b3[tid];
    }
    for (int idx = tid; idx < 768; idx += TPB) lw4[idx] = w4[idx];
    if (tid < 6) lb4v[tid] = b4[tid];
    if (tid < 8) {
        st2[tid] = inp[16 + tid];
        st3[tid] = inp[24 + tid];
        st4[tid] = inp[32 + tid];
        lbw[tid] = inp[48 + tid];
    }
    if (tid == 0) {
        sx[0] = inp[7];   sx[1] = inp[15];
        sx[2] = inp[39];  sx[3] = inp[32];
        sx[4] = inp[56];
    }
    __syncthreads();

    // ---- constant-across-steps speculative feats ----
    if (tid < 128) {
        const float vb[6] = {300.f, 750.f, 1200.f, 1850.f, 2850.f, 4300.f};
        #pragma unroll
        for (int v = 0; v < 6; ++v)
            ls0[v * 128 + tid] = relu_(vb[v] * (1.f / 4300.f) * lw0v[tid] + lb0v[tid]);
        ltmp[tid] = relu_(3.0f * lw1v[tid] + lb1v[tid]);       // s1 after any update
    }
    for (int m = tid; m < 384; m += TPB) {                     // s4 after any update
        int c = m / 3, w = m - c * 3;
        float a = lcb[c];
        #pragma unroll
        for (int k = 0; k < 4; ++k)
            a += sx[4] * (float)(1 << (w + k)) * 1e-6f * lcw[c * 4 + k];
        ltmp[128 + m] = relu_(a);
    }
    __syncthreads();

    const int wv = tid >> 6, lane = tid & 63;
    const float* wr = lw3 + wv * 2048;                          // this wave's w3 row
    const float bias3 = lb3v[b * 4 + wv];

    // per-lane constant dot-partials: hs0p[v] (s0 variants), hs14p (s1+s4)
    float hs0p[6], hs14p;
    #pragma unroll
    for (int v = 0; v < 6; ++v)
        hs0p[v] = wr[lane] * ls0[v * 128 + lane] + wr[64 + lane] * ls0[v * 128 + 64 + lane];
    hs14p = wr[128 + lane] * ltmp[lane] + wr[192 + lane] * ltmp[64 + lane];
    #pragma unroll
    for (int k = 0; k < 6; ++k) {
        int m = lane + 64 * k;
        hs14p += wr[1536 + m] * ltmp[128 + m];
    }

    const float VBRc[6] = {300.f, 750.f, 1200.f, 1850.f, 2850.f, 4300.f};

    for (int g = 0; g < 2; ++g) {
        const int i = 2 * g;

        // ---- Phase A: feat_i (exact) + next-step common pieces ----
        if (tid < 128) {
            lfeat[tid]        = relu_(sx[0] * lw0v[tid] + lb0v[tid]);   // s0
            lfeat[1920 + tid] =        sx[2] * lw2v[tid] + lb2v[tid];   // s5 (no relu)
            lbase2[tid] = st2[5] * lcw[tid*4] + st2[6] * lcw[tid*4+1]
                        + st2[7] * lcw[tid*4+2] + lcb[tid];
            lbase3[tid] = st3[5] * lcw[tid*4] + st3[6] * lcw[tid*4+1]
                        + st3[7] * lcw[tid*4+2] + lcb[tid];
            ls5[tid] = sx[3] * lw2v[tid] + lb2v[tid];                   // next s5
        } else {
            int j = tid - 128;
            lfeat[128 + j] = relu_(sx[1] * lw1v[j] + lb1v[j]);          // s1
        }
        for (int m = tid; m < 640; m += TPB) {                          // s2, s3
            int c = m / 5, w = m - c * 5;
            float a2 = lcb[c], a3 = lcb[c];
            #pragma unroll
            for (int k = 0; k < 4; ++k) {
                float cw = lcw[c * 4 + k];
                a2 += st2[w + k] * cw;
                a3 += st3[w + k] * cw;
            }
            lfeat[256 + m] = relu_(a2);
            lfeat[896 + m] = relu_(a3);
        }
        for (int m = tid; m < 384; m += TPB) {                          // s4
            int c = m / 3, w = m - c * 3;
            float a4 = lcb[c];
            #pragma unroll
            for (int k = 0; k < 4; ++k) a4 += st4[w + k] * lcw[c * 4 + k];
            lfeat[1536 + m] = relu_(a4);
        }
        for (int m = tid; m < 512; m += TPB) {       // next-step s2/s3 windows 0..3
            int c = m >> 2, w = m & 3;
            float a2 = lcb[c], a3 = lcb[c];
            #pragma unroll
            for (int k = 0; k < 4; ++k) {
                float cw = lcw[c * 4 + k];
                a2 += st2[w + 1 + k] * cw;
                a3 += st3[w + 1 + k] * cw;
            }
            lc2[m] = relu_(a2);
            lc3[m] = relu_(a3);
        }
        __syncthreads();

        // ---- Phase B: wave dots ----
        float acc_i;
        {
            const float4* w4p = (const float4*)wr;
            const float4* f4p = (const float4*)lfeat;
            float4 acc = make_float4(0.f, 0.f, 0.f, 0.f);
            #pragma unroll
            for (int it = 0; it < 8; ++it) {
                float4 a = w4p[it * 64 + lane];
                float4 f = f4p[it * 64 + lane];
                acc.x += a.x * f.x; acc.y += a.y * f.y;
                acc.z += a.z * f.z; acc.w += a.w * f.w;
            }
            acc_i = (acc.x + acc.y) + (acc.z + acc.w);
        }

        float acc_c = hs14p
                    + wr[1920 + lane] * ls5[lane]
                    + wr[1984 + lane] * ls5[64 + lane];
        #pragma unroll
        for (int k = 0; k < 8; ++k) {
            int m = lane + 64 * k;
            int col = 256 + (m >> 2) * 5 + (m & 3);
            acc_c += wr[col] * lc2[m] + wr[640 + col] * lc3[m];
        }

        float n2[6], n3[6];
        {
            float bwi = lbw[i], vs = sx[4];
            #pragma unroll
            for (int v = 0; v < 6; ++v) {
                float vca   = vs * (float)(1 << v);
                float delay = vca / bwi - 30000.f;
                n2[v] = vca / delay * 1e-3f;
                n3[v] = delay * 1e-4f;
            }
        }
        float accv[6];
        #pragma unroll
        for (int v = 0; v < 6; ++v) accv[v] = hs0p[v];
        #pragma unroll
        for (int t = 0; t < 2; ++t) {
            int c = lane + 64 * t;
            float cw3 = lcw[c * 4 + 3];
            float bb2 = lbase2[c], bb3 = lbase3[c];
            float wc2 = wr[256 + c * 5 + 4], wc3 = wr[896 + c * 5 + 4];
            #pragma unroll
            for (int v = 0; v < 6; ++v)
                accv[v] += relu_(bb2 + n2[v] * cw3) * wc2
                         + relu_(bb3 + n3[v] * cw3) * wc3;
        }

        #pragma unroll
        for (int off = 32; off > 0; off >>= 1) {
            acc_i += __shfl_xor(acc_i, off);
            acc_c += __shfl_xor(acc_c, off);
            #pragma unroll
            for (int v = 0; v < 6; ++v) accv[v] += __shfl_xor(accv[v], off);
        }
        if (lane == 0) {
            h_lds[wv] = relu_(acc_i + bias3);
            #pragma unroll
            for (int v = 0; v < 6; ++v)
                hv_lds[wv * 8 + v] = relu_(acc_c + accv[v] + bias3);
        }
        __syncthreads();

        // ---- Phase C: publish 42 partial logits + flag ----
        if (tid < 42) {
            int q = tid / 6, t = tid - q * 6;
            float p = 0.f;
            if (q == 0) {
                #pragma unroll
                for (int w = 0; w < 4; ++w) p += lw4[t * 128 + b * 4 + w] * h_lds[w];
            } else {
                #pragma unroll
                for (int w = 0; w < 4; ++w) p += lw4[t * 128 + b * 4 + w] * hv_lds[w * 8 + (q - 1)];
            }
            __hip_atomic_store(&partials[(g * NBLK + b) * PSTRIDE + tid], p,
                               __ATOMIC_RELAXED, __HIP_MEMORY_SCOPE_AGENT);
        }
        __syncthreads();
        if (tid == 0)
            __hip_atomic_store(&flags[b * FSTRIDE], g + 1,
                               __ATOMIC_RELEASE, __HIP_MEMORY_SCOPE_AGENT);
        if (tid < NBLK) {
            while (__hip_atomic_load(&flags[tid * FSTRIDE], __ATOMIC_ACQUIRE,
                                     __HIP_MEMORY_SCOPE_AGENT) < g + 1)
                __builtin_amdgcn_s_sleep(1);
        }
        __syncthreads();

        // ---- Phase D: fan-in reduce, double argmax, double state update ----
        if (tid < 42) {
            float p = lb4v[tid % 6];
            #pragma unroll
            for (int bb = 0; bb < NBLK; ++bb)
                p += __hip_atomic_load(&partials[(g * NBLK + bb) * PSTRIDE + tid],
                                       __ATOMIC_RELAXED, __HIP_MEMORY_SCOPE_AGENT);
            red[tid] = p;
        }
        __syncthreads();
        if (tid == 0) {
            float best = red[0]; int a0 = 0;
            #pragma unroll
            for (int r = 1; r < 6; ++r) if (red[r] > best) { best = red[r]; a0 = r; }
            best = red[6 + 6 * a0]; int a1 = 0;
            #pragma unroll
            for (int r = 1; r < 6; ++r)
                if (red[6 + 6 * a0 + r] > best) { best = red[6 + 6 * a0 + r]; a1 = r; }

            // update(i, a0)
            {
                float vca = sx[4] * (float)(1 << a0);
                float delay = vca / lbw[i] - 30000.f;
                sx[0] = VBRc[a0] * (1.f / 4300.f);
                sx[1] = 3.0f;
                #pragma unroll
                for (int c = 0; c < 7; ++c) { st2[c] = st2[c + 1]; st3[c] = st3[c + 1]; }
                st2[7] = vca / delay * 1e-3f;
                st3[7] = delay * 1e-4f;
                sx[2] = sx[3]; sx[3] = sx[4] * 1e-6f;
                #pragma unroll
                for (int j = 0; j < 6; ++j) st4[j] = sx[4] * (float)(1 << j) * 1e-6f;
            }
            // update(i+1, a1)
            {
                float vca = sx[4] * (float)(1 << a1);
                float delay = vca / lbw[i + 1] - 30000.f;
                sx[0] = VBRc[a1] * (1.f / 4300.f);
                sx[1] = 3.0f;
                #pragma unroll
                for (int c = 0; c < 7; ++c) { st2[c] = st2[c + 1]; st3[c] = st3[c + 1]; }
                st2[7] = vca / delay * 1e-3f;
                st3[7] = delay * 1e-4f;
                sx[2] = sx[3]; sx[3] = sx[4] * 1e-6f;
                #pragma unroll
                for (int j = 0; j < 6; ++j) st4[j] = sx[4] * (float)(1 << j) * 1e-6f;
            }
        }
        __syncthreads();
    }

    // ================= group 2: steps 4,5 + speculated FINAL =================
    {
        const int i = 4;

        // ---- Phase A (same as loop) ----
        if (tid < 128) {
            lfeat[tid]        = relu_(sx[0] * lw0v[tid] + lb0v[tid]);
            lfeat[1920 + tid] =        sx[2] * lw2v[tid] + lb2v[tid];
            lbase2[tid] = st2[5] * lcw[tid*4] + st2[6] * lcw[tid*4+1]
                        + st2[7] * lcw[tid*4+2] + lcb[tid];
            lbase3[tid] = st3[5] * lcw[tid*4] + st3[6] * lcw[tid*4+1]
                        + st3[7] * lcw[tid*4+2] + lcb[tid];
            ls5[tid] = sx[3] * lw2v[tid] + lb2v[tid];   // == final s5 too (st[4,7]=vs*1e-6)
        } else {
            int j = tid - 128;
            lfeat[128 + j] = relu_(sx[1] * lw1v[j] + lb1v[j]);
        }
        for (int m = tid; m < 640; m += TPB) {
            int c = m / 5, w = m - c * 5;
            float a2 = lcb[c], a3 = lcb[c];
            #pragma unroll
            for (int k = 0; k < 4; ++k) {
                float cw = lcw[c * 4 + k];
                a2 += st2[w + k] * cw;
                a3 += st3[w + k] * cw;
            }
            lfeat[256 + m] = relu_(a2);
            lfeat[896 + m] = relu_(a3);
        }
        for (int m = tid; m < 384; m += TPB) {
            int c = m / 3, w = m - c * 3;
            float a4 = lcb[c];
            #pragma unroll
            for (int k = 0; k < 4; ++k) a4 += st4[w + k] * lcw[c * 4 + k];
            lfeat[1536 + m] = relu_(a4);
        }
        for (int m = tid; m < 512; m += TPB) {
            int c = m >> 2, w = m & 3;
            float a2 = lcb[c], a3 = lcb[c];
            #pragma unroll
            for (int k = 0; k < 4; ++k) {
                float cw = lcw[c * 4 + k];
                a2 += st2[w + 1 + k] * cw;
                a3 += st3[w + 1 + k] * cw;
            }
            lc2[m] = relu_(a2);
            lc3[m] = relu_(a3);
        }
        __syncthreads();

        // ---- Phase B ----
        float acc_i;
        {
            const float4* w4p = (const float4*)wr;
            const float4* f4p = (const float4*)lfeat;
            float4 acc = make_float4(0.f, 0.f, 0.f, 0.f);
            #pragma unroll
            for (int it = 0; it < 8; ++it) {
                float4 a = w4p[it * 64 + lane];
                float4 f = f4p[it * 64 + lane];
                acc.x += a.x * f.x; acc.y += a.y * f.y;
                acc.z += a.z * f.z; acc.w += a.w * f.w;
            }
            acc_i = (acc.x + acc.y) + (acc.z + acc.w);
        }

        float s5c = wr[1920 + lane] * ls5[lane] + wr[1984 + lane] * ls5[64 + lane];
        float acc_c = hs14p + s5c;
        #pragma unroll
        for (int k = 0; k < 8; ++k) {
            int m = lane + 64 * k;
            int col = 256 + (m >> 2) * 5 + (m & 3);
            acc_c += wr[col] * lc2[m] + wr[640 + col] * lc3[m];
        }

        float n24[6], n34[6], n25[6], n35[6];
        {
            float bw4 = lbw[4], bw5 = lbw[5], vs = sx[4];
            #pragma unroll
            for (int v = 0; v < 6; ++v) {
                float vca = vs * (float)(1 << v);
                float d4  = vca / bw4 - 30000.f;
                float d5  = vca / bw5 - 30000.f;
                n24[v] = vca / d4 * 1e-3f;  n34[v] = d4 * 1e-4f;
                n25[v] = vca / d5 * 1e-3f;  n35[v] = d5 * 1e-4f;
            }
        }

        // per-channel registers for this lane's two channels
        float cw0a[2], cw1a[2], cw2a[2], cw3a[2], lb2a[2], lb3a[2];
        float wc2a[2], wc3a[2], w3s2[2], w3s3[2], b42a[2], b43a[2];
        float fcom = hs14p + s5c;   // final common: s1+s4+s5 + windows 0..2
        #pragma unroll
        for (int t = 0; t < 2; ++t) {
            int c = lane + 64 * t;
            cw0a[t] = lcw[c*4];   cw1a[t] = lcw[c*4+1];
            cw2a[t] = lcw[c*4+2]; cw3a[t] = lcw[c*4+3];
            lb2a[t] = lbase2[c];  lb3a[t] = lbase3[c];
            wc2a[t] = wr[256 + c*5 + 4]; wc3a[t] = wr[896 + c*5 + 4];
            w3s2[t] = wr[256 + c*5 + 3]; w3s3[t] = wr[896 + c*5 + 3];
            b42a[t] = st2[6]*cw0a[t] + st2[7]*cw1a[t] + lcb[c];
            b43a[t] = st3[6]*cw0a[t] + st3[7]*cw1a[t] + lcb[c];
            #pragma unroll
            for (int w = 0; w < 3; ++w) {
                float a2 = st2[2+w]*cw0a[t] + st2[3+w]*cw1a[t]
                         + st2[4+w]*cw2a[t] + st2[5+w]*cw3a[t] + lcb[c];
                float a3 = st3[2+w]*cw0a[t] + st3[3+w]*cw1a[t]
                         + st3[4+w]*cw2a[t] + st3[5+w]*cw3a[t] + lcb[c];
                fcom += relu_(a2) * wr[256 + c*5 + w] + relu_(a3) * wr[896 + c*5 + w];
            }
        }

        float accv[6], accf[36];
        #pragma unroll
        for (int v4 = 0; v4 < 6; ++v4) {
            float av = hs0p[v4];
            float fv4 = fcom;
            #pragma unroll
            for (int t = 0; t < 2; ++t) {
                float r2 = relu_(lb2a[t] + n24[v4] * cw3a[t]);
                float r3 = relu_(lb3a[t] + n34[v4] * cw3a[t]);
                av  += r2 * wc2a[t] + r3 * wc3a[t];     // step-5 window-4 variant
                fv4 += r2 * w3s2[t] + r3 * w3s3[t];     // final window-3 (same relu!)
            }
            accv[v4] = av;
            #pragma unroll
            for (int v5 = 0; v5 < 6; ++v5) {
                float s = fv4 + hs0p[v5];
                #pragma unroll
                for (int t = 0; t < 2; ++t) {
                    s += relu_(b42a[t] + n24[v4]*cw2a[t] + n25[v5]*cw3a[t]) * wc2a[t]
                       + relu_(b43a[t] + n34[v4]*cw2a[t] + n35[v5]*cw3a[t]) * wc3a[t];
                }
                accf[v4 * 6 + v5] = s;
            }
        }

        #pragma unroll
        for (int off = 32; off > 0; off >>= 1) {
            acc_i += __shfl_xor(acc_i, off);
            acc_c += __shfl_xor(acc_c, off);
            #pragma unroll
            for (int v = 0; v < 6; ++v) accv[v] += __shfl_xor(accv[v], off);
            #pragma unroll
            for (int v = 0; v < 36; ++v) accf[v] += __shfl_xor(accf[v], off);
        }
        if (lane == 0) {
            h_lds[wv] = relu_(acc_i + bias3);
            #pragma unroll
            for (int v = 0; v < 6; ++v)
                hv_lds[wv * 8 + v] = relu_(acc_c + accv[v] + bias3);
            #pragma unroll
            for (int v = 0; v < 36; ++v)
                hf_lds[wv * 40 + v] = relu_(accf[v] + bias3);
        }
        __syncthreads();

        // ---- publish 42 + 216 partial logits ----
        float* slot = &partials[(2 * NBLK + b) * PSTRIDE];
        if (tid < 42) {
            int q = tid / 6, t = tid - q * 6;
            float p = 0.f;
            if (q == 0) {
                #pragma unroll
                for (int w = 0; w < 4; ++w) p += lw4[t * 128 + b * 4 + w] * h_lds[w];
            } else {
                #pragma unroll
                for (int w = 0; w < 4; ++w) p += lw4[t * 128 + b * 4 + w] * hv_lds[w * 8 + (q - 1)];
            }
            __hip_atomic_store(&slot[tid], p, __ATOMIC_RELAXED, __HIP_MEMORY_SCOPE_AGENT);
        }
        if (tid < 216) {
            int combo = tid / 6, t = tid - combo * 6;
            float p = 0.f;
            #pragma unroll
            for (int w = 0; w < 4; ++w) p += lw4[t * 128 + b * 4 + w] * hf_lds[w * 40 + combo];
            __hip_atomic_store(&slot[42 + tid], p, __ATOMIC_RELAXED, __HIP_MEMORY_SCOPE_AGENT);
        }
        __syncthreads();
        if (tid == 0)
            __hip_atomic_store(&flags[b * FSTRIDE], 3,
                               __ATOMIC_RELEASE, __HIP_MEMORY_SCOPE_AGENT);

        // ---- only block 0 resolves the last sync and writes out ----
        if (b == 0) {
            if (tid < NBLK) {
                while (__hip_atomic_load(&flags[tid * FSTRIDE], __ATOMIC_ACQUIRE,
                                         __HIP_MEMORY_SCOPE_AGENT) < 3)
                    __builtin_amdgcn_s_sleep(1);
            }
            __syncthreads();
            for (int v = tid; v < 258; v += TPB) {
                float p = lb4v[v % 6];          // 42 % 6 == 0 -> v%6 works for finals too
                #pragma unroll
                for (int bb = 0; bb < NBLK; ++bb)
                    p += __hip_atomic_load(&partials[(2 * NBLK + bb) * PSTRIDE + v],
                                           __ATOMIC_RELAXED, __HIP_MEMORY_SCOPE_AGENT);
                red2[v] = p;
            }
            __syncthreads();
            if (tid == 0) {
                float best = red2[0]; int a4 = 0;
                #pragma unroll
                for (int r = 1; r < 6; ++r) if (red2[r] > best) { best = red2[r]; a4 = r; }
                best = red2[6 + 6 * a4]; int a5 = 0;
                #pragma unroll
                for (int r = 1; r < 6; ++r)
                    if (red2[6 + 6 * a4 + r] > best) { best = red2[6 + 6 * a4 + r]; a5 = r; }
                ssel = a4 * 6 + a5;
            }
            __syncthreads();
            if (tid < 6) out[tid] = red2[42 + ssel * 6 + tid];
        }
    }
}

extern "C" void kernel_launch(void* const* d_in, const int* in_sizes, int n_in,
                              void* d_out, int out_size, void* d_ws, size_t ws_size,
                              hipStream_t stream) {
    const float* inp    = (const float*)d_in[0];
    const float* conv_w = (const float*)d_in[1];
    const float* conv_b = (const float*)d_in[2];
    const float* w0     = (const float*)d_in[3];
    const float* b0     = (const float*)d_in[4];
    const float* w1     = (const float*)d_in[5];
    const float* b1     = (const float*)d_in[6];
    const float* w2     = (const float*)d_in[7];
    const float* b2     = (const float*)d_in[8];
    const float* w3     = (const float*)d_in[9];
    const float* b3     = (const float*)d_in[10];
    const float* w4     = (const float*)d_in[11];
    const float* b4     = (const float*)d_in[12];

    int*   flags    = (int*)d_ws;                       // 32 flags, 128 B apart
    float* partials = (float*)((char*)d_ws + 8192);     // 3*32 slots * 1280 B

    actor_kernel<<<NBLK, TPB, 0, stream>>>(inp, conv_w, conv_b,
                                           w0, b0, w1, b1, w2, b2,
                                           w3, b3, w4, b4,
                                           (float*)d_out, flags, partials);
}

// Round 6
// 99.844 us; speedup vs baseline: 1.1384x; 1.0238x over previous
//
#include <hip/hip_runtime.h>

#define NBLK 32
#define TPB  256
#define FSTRIDE 32  // flag spacing in ints = 128 B, one cacheline per block
#define PSTRIDE 64  // publish slot stride in floats (256 B)

__device__ __forceinline__ float relu_(float x) { return fmaxf(x, 0.f); }

// R3 4-sync structure (best: 99.9), with the final eval collapsed:
//  group g (g=0,1,2): step 2g exact + 6 speculated step-(2g+1) variants,
//  publish 42 partial logits, one grid sync resolves both argmaxes.
//  FINAL phase: pre-resolve parts (s1,s4,s5,win0..2) captured in registers
//  during group-2 Phase B; post-resolve only win3/win4/s0(a5) (~50 ops),
//  one shfl chain, publish 6, sync 4 (block 0 only), write out.
//  Flags monotone 1..4; poison 0xAAAAAAAA is negative -> no init kernel.

__launch_bounds__(TPB, 1)
__global__ void actor_kernel(
    const float* __restrict__ inp,
    const float* __restrict__ conv_w, const float* __restrict__ conv_b,
    const float* __restrict__ w0, const float* __restrict__ b0,
    const float* __restrict__ w1, const float* __restrict__ b1,
    const float* __restrict__ w2, const float* __restrict__ b2,
    const float* __restrict__ w3, const float* __restrict__ b3,
    const float* __restrict__ w4, const float* __restrict__ b4,
    float* __restrict__ out, int* __restrict__ flags,
    float* __restrict__ partials)
{
    const int tid = threadIdx.x;
    const int b   = blockIdx.x;

    __shared__ __align__(16) float lw3[4 * 2048];    // 32 KB row slice
    __shared__ __align__(16) float lfeat[2048];
    __shared__ __align__(16) float lc2[512], lc3[512]; // next-step common conv feats
    __shared__ float lbase2[128], lbase3[128], ls5[128];
    __shared__ float ls0[6 * 128];                   // 6 s0 variants (constant)
    __shared__ float ltmp[512];                      // s1c (128) + s4c (384), constant
    __shared__ __align__(16) float lcw[512];
    __shared__ float lcb[128];
    __shared__ float lw0v[128], lb0v[128], lw1v[128], lb1v[128];
    __shared__ float lw2v[128], lb2v[128], lb3v[128];
    __shared__ float lw4[768], lb4v[8];
    __shared__ float st2[8], st3[8], st4[8];
    __shared__ float sx[8];     // 0:st[0,7] 1:st[1,7] 2:st[4,7] 3:st[4,0] 4:vs
    __shared__ float lbw[8];
    __shared__ float h_lds[4], hv_lds[4 * 8];
    __shared__ float red[48];
    __shared__ float s_red[192];
    __shared__ int   sact[2];

    // ---- one-time staging ----
    {
        const float4* g4 = (const float4*)(w3 + b * 4 * 2048);
        float4* l4 = (float4*)lw3;
        for (int idx = tid; idx < 2048; idx += TPB) l4[idx] = g4[idx];
    }
    for (int idx = tid; idx < 512; idx += TPB) lcw[idx] = conv_w[idx];
    if (tid < 128) {
        lcb[tid]  = conv_b[tid];
        lw0v[tid] = w0[tid]; lb0v[tid] = b0[tid];
        lw1v[tid] = w1[tid]; lb1v[tid] = b1[tid];
        lw2v[tid] = w2[tid]; lb2v[tid] = b2[tid];
        lb3v[tid] = b3[tid];
    }
    for (int idx = tid; idx < 768; idx += TPB) lw4[idx] = w4[idx];
    if (tid < 6) lb4v[tid] = b4[tid];
    if (tid < 8) {
        st2[tid] = inp[16 + tid];
        st3[tid] = inp[24 + tid];
        st4[tid] = inp[32 + tid];
        lbw[tid] = inp[48 + tid];
    }
    if (tid == 0) {
        sx[0] = inp[7];   sx[1] = inp[15];
        sx[2] = inp[39];  sx[3] = inp[32];
        sx[4] = inp[56];
    }
    __syncthreads();

    // ---- constant-across-steps speculative feats ----
    if (tid < 128) {
        const float vb[6] = {300.f, 750.f, 1200.f, 1850.f, 2850.f, 4300.f};
        #pragma unroll
        for (int v = 0; v < 6; ++v)
            ls0[v * 128 + tid] = relu_(vb[v] * (1.f / 4300.f) * lw0v[tid] + lb0v[tid]);
        ltmp[tid] = relu_(3.0f * lw1v[tid] + lb1v[tid]);       // s1 after any update
    }
    for (int m = tid; m < 384; m += TPB) {                     // s4 after any update
        int c = m / 3, w = m - c * 3;
        float a = lcb[c];
        #pragma unroll
        for (int k = 0; k < 4; ++k)
            a += sx[4] * (float)(1 << (w + k)) * 1e-6f * lcw[c * 4 + k];
        ltmp[128 + m] = relu_(a);
    }
    __syncthreads();

    const int wv = tid >> 6, lane = tid & 63;
    const float* wr = lw3 + wv * 2048;                          // this wave's w3 row
    const float bias3 = lb3v[b * 4 + wv];

    // per-lane constant dot-partials: hs0p[v] (s0 variants), hs14p (s1+s4)
    float hs0p[6], hs14p;
    #pragma unroll
    for (int v = 0; v < 6; ++v)
        hs0p[v] = wr[lane] * ls0[v * 128 + lane] + wr[64 + lane] * ls0[v * 128 + 64 + lane];
    hs14p = wr[128 + lane] * ltmp[lane] + wr[192 + lane] * ltmp[64 + lane];
    #pragma unroll
    for (int k = 0; k < 6; ++k) {
        int m = lane + 64 * k;
        hs14p += wr[1536 + m] * ltmp[128 + m];
    }

    const float VBRc[6] = {300.f, 750.f, 1200.f, 1850.f, 2850.f, 4300.f};

    // final-phase captures (filled during g==2 Phase B)
    float fcom_f = 0.f;
    float lb2s[2], lb3s[2], b4f2[2], b4f3[2];
    float cw2s[2], cw3s[2], w32s[2], w33s[2], w42s[2], w43s[2];

    for (int g = 0; g < 3; ++g) {
        const int i = 2 * g;

        // ---- Phase A: feat_i (exact) + next-step common pieces ----
        if (tid < 128) {
            lfeat[tid]        = relu_(sx[0] * lw0v[tid] + lb0v[tid]);   // s0
            lfeat[1920 + tid] =        sx[2] * lw2v[tid] + lb2v[tid];   // s5 (no relu)
            lbase2[tid] = st2[5] * lcw[tid*4] + st2[6] * lcw[tid*4+1]
                        + st2[7] * lcw[tid*4+2] + lcb[tid];
            lbase3[tid] = st3[5] * lcw[tid*4] + st3[6] * lcw[tid*4+1]
                        + st3[7] * lcw[tid*4+2] + lcb[tid];
            ls5[tid] = sx[3] * lw2v[tid] + lb2v[tid];                   // next s5
        } else {
            int j = tid - 128;
            lfeat[128 + j] = relu_(sx[1] * lw1v[j] + lb1v[j]);          // s1
        }
        for (int m = tid; m < 640; m += TPB) {                          // s2, s3
            int c = m / 5, w = m - c * 5;
            float a2 = lcb[c], a3 = lcb[c];
            #pragma unroll
            for (int k = 0; k < 4; ++k) {
                float cw = lcw[c * 4 + k];
                a2 += st2[w + k] * cw;
                a3 += st3[w + k] * cw;
            }
            lfeat[256 + m] = relu_(a2);
            lfeat[896 + m] = relu_(a3);
        }
        for (int m = tid; m < 384; m += TPB) {                          // s4
            int c = m / 3, w = m - c * 3;
            float a4 = lcb[c];
            #pragma unroll
            for (int k = 0; k < 4; ++k) a4 += st4[w + k] * lcw[c * 4 + k];
            lfeat[1536 + m] = relu_(a4);
        }
        for (int m = tid; m < 512; m += TPB) {       // next-step s2/s3 windows 0..3
            int c = m >> 2, w = m & 3;
            float a2 = lcb[c], a3 = lcb[c];
            #pragma unroll
            for (int k = 0; k < 4; ++k) {
                float cw = lcw[c * 4 + k];
                a2 += st2[w + 1 + k] * cw;
                a3 += st3[w + 1 + k] * cw;
            }
            lc2[m] = relu_(a2);
            lc3[m] = relu_(a3);
        }
        __syncthreads();

        // ---- Phase B: wave dots ----
        float acc_i;
        {
            const float4* w4p = (const float4*)wr;
            const float4* f4p = (const float4*)lfeat;
            float4 acc = make_float4(0.f, 0.f, 0.f, 0.f);
            #pragma unroll
            for (int it = 0; it < 8; ++it) {
                float4 a = w4p[it * 64 + lane];
                float4 f = f4p[it * 64 + lane];
                acc.x += a.x * f.x; acc.y += a.y * f.y;
                acc.z += a.z * f.z; acc.w += a.w * f.w;
            }
            acc_i = (acc.x + acc.y) + (acc.z + acc.w);
        }

        float s5c = wr[1920 + lane] * ls5[lane] + wr[1984 + lane] * ls5[64 + lane];
        float acc_c = hs14p + s5c;
        #pragma unroll
        for (int k = 0; k < 8; ++k) {
            int m = lane + 64 * k;
            int col = 256 + (m >> 2) * 5 + (m & 3);
            acc_c += wr[col] * lc2[m] + wr[640 + col] * lc3[m];
        }

        float n2[6], n3[6];
        {
            float bwi = lbw[i], vs = sx[4];
            #pragma unroll
            for (int v = 0; v < 6; ++v) {
                float vca   = vs * (float)(1 << v);
                float delay = vca / bwi - 30000.f;
                n2[v] = vca / delay * 1e-3f;
                n3[v] = delay * 1e-4f;
            }
        }
        float accv[6];
        #pragma unroll
        for (int v = 0; v < 6; ++v) accv[v] = hs0p[v];
        #pragma unroll
        for (int t = 0; t < 2; ++t) {
            int c = lane + 64 * t;
            float cw3 = lcw[c * 4 + 3];
            float bb2 = lbase2[c], bb3 = lbase3[c];
            float wc2 = wr[256 + c * 5 + 4], wc3 = wr[896 + c * 5 + 4];
            #pragma unroll
            for (int v = 0; v < 6; ++v)
                accv[v] += relu_(bb2 + n2[v] * cw3) * wc2
                         + relu_(bb3 + n3[v] * cw3) * wc3;
        }

        // ---- g==2: capture final-eval pre-resolve parts (pure registers) ----
        if (g == 2) {
            fcom_f = hs14p + s5c;       // s1 + s4 + s5 of final state
            #pragma unroll
            for (int t = 0; t < 2; ++t) {
                int c = lane + 64 * t;
                float c0 = lcw[c*4], c1 = lcw[c*4+1], c2 = lcw[c*4+2], c3 = lcw[c*4+3];
                cw2s[t] = c2; cw3s[t] = c3;
                lb2s[t] = lbase2[c];  lb3s[t] = lbase3[c];   // final win3 base
                b4f2[t] = st2[6]*c0 + st2[7]*c1 + lcb[c];    // final win4 base (s2)
                b4f3[t] = st3[6]*c0 + st3[7]*c1 + lcb[c];    // final win4 base (s3)
                w32s[t] = wr[256 + c*5 + 3]; w33s[t] = wr[896 + c*5 + 3];
                w42s[t] = wr[256 + c*5 + 4]; w43s[t] = wr[896 + c*5 + 4];
                #pragma unroll
                for (int w = 0; w < 3; ++w) {                // final win0..2 (known now)
                    float a2 = st2[2+w]*c0 + st2[3+w]*c1 + st2[4+w]*c2 + st2[5+w]*c3 + lcb[c];
                    float a3 = st3[2+w]*c0 + st3[3+w]*c1 + st3[4+w]*c2 + st3[5+w]*c3 + lcb[c];
                    fcom_f += relu_(a2) * wr[256 + c*5 + w] + relu_(a3) * wr[896 + c*5 + w];
                }
            }
        }

        #pragma unroll
        for (int off = 32; off > 0; off >>= 1) {
            acc_i += __shfl_xor(acc_i, off);
            acc_c += __shfl_xor(acc_c, off);
            #pragma unroll
            for (int v = 0; v < 6; ++v) accv[v] += __shfl_xor(accv[v], off);
        }
        if (lane == 0) {
            h_lds[wv] = relu_(acc_i + bias3);
            #pragma unroll
            for (int v = 0; v < 6; ++v)
                hv_lds[wv * 8 + v] = relu_(acc_c + accv[v] + bias3);
        }
        __syncthreads();

        // ---- Phase C: publish 42 partial logits + flag ----
        if (tid < 42) {
            int q = tid / 6, t = tid - q * 6;
            float p = 0.f;
            if (q == 0) {
                #pragma unroll
                for (int w = 0; w < 4; ++w) p += lw4[t * 128 + b * 4 + w] * h_lds[w];
            } else {
                #pragma unroll
                for (int w = 0; w < 4; ++w) p += lw4[t * 128 + b * 4 + w] * hv_lds[w * 8 + (q - 1)];
            }
            __hip_atomic_store(&partials[(g * NBLK + b) * PSTRIDE + tid], p,
                               __ATOMIC_RELAXED, __HIP_MEMORY_SCOPE_AGENT);
        }
        __syncthreads();
        if (tid == 0)
            __hip_atomic_store(&flags[b * FSTRIDE], g + 1,
                               __ATOMIC_RELEASE, __HIP_MEMORY_SCOPE_AGENT);
        if (tid < NBLK) {
            while (__hip_atomic_load(&flags[tid * FSTRIDE], __ATOMIC_ACQUIRE,
                                     __HIP_MEMORY_SCOPE_AGENT) < g + 1)
                __builtin_amdgcn_s_sleep(1);
        }
        __syncthreads();

        // ---- Phase D: fan-in reduce, double argmax, double state update ----
        if (tid < 42) {
            float p = lb4v[tid % 6];
            #pragma unroll
            for (int bb = 0; bb < NBLK; ++bb)
                p += __hip_atomic_load(&partials[(g * NBLK + bb) * PSTRIDE + tid],
                                       __ATOMIC_RELAXED, __HIP_MEMORY_SCOPE_AGENT);
            red[tid] = p;
        }
        __syncthreads();
        if (tid == 0) {
            float best = red[0]; int a0 = 0;
            #pragma unroll
            for (int r = 1; r < 6; ++r) if (red[r] > best) { best = red[r]; a0 = r; }
            best = red[6 + 6 * a0]; int a1 = 0;
            #pragma unroll
            for (int r = 1; r < 6; ++r)
                if (red[6 + 6 * a0 + r] > best) { best = red[6 + 6 * a0 + r]; a1 = r; }

            if (g == 2) {
                sact[0] = a0; sact[1] = a1;   // states no longer needed
            } else {
                // update(i, a0)
                {
                    float vca = sx[4] * (float)(1 << a0);
                    float delay = vca / lbw[i] - 30000.f;
                    sx[0] = VBRc[a0] * (1.f / 4300.f);
                    sx[1] = 3.0f;
                    #pragma unroll
                    for (int c = 0; c < 7; ++c) { st2[c] = st2[c + 1]; st3[c] = st3[c + 1]; }
                    st2[7] = vca / delay * 1e-3f;
                    st3[7] = delay * 1e-4f;
                    sx[2] = sx[3]; sx[3] = sx[4] * 1e-6f;
                    #pragma unroll
                    for (int j = 0; j < 6; ++j) st4[j] = sx[4] * (float)(1 << j) * 1e-6f;
                }
                // update(i+1, a1)
                {
                    float vca = sx[4] * (float)(1 << a1);
                    float delay = vca / lbw[i + 1] - 30000.f;
                    sx[0] = VBRc[a1] * (1.f / 4300.f);
                    sx[1] = 3.0f;
                    #pragma unroll
                    for (int c = 0; c < 7; ++c) { st2[c] = st2[c + 1]; st3[c] = st3[c + 1]; }
                    st2[7] = vca / delay * 1e-3f;
                    st3[7] = delay * 1e-4f;
                    sx[2] = sx[3]; sx[3] = sx[4] * 1e-6f;
                    #pragma unroll
                    for (int j = 0; j < 6; ++j) st4[j] = sx[4] * (float)(1 << j) * 1e-6f;
                }
            }
        }
        __syncthreads();
    }

    // ---- final eval: ~50 ops from captured registers, one shfl chain ----
    {
        const int a4 = sact[0], a5 = sact[1];
        float vs = sx[4];
        float vca4 = vs * (float)(1 << a4);
        float d4   = vca4 / lbw[4] - 30000.f;
        float ap24 = vca4 / d4 * 1e-3f, ap34 = d4 * 1e-4f;
        float vca5 = vs * (float)(1 << a5);
        float d5   = vca5 / lbw[5] - 30000.f;
        float ap25 = vca5 / d5 * 1e-3f, ap35 = d5 * 1e-4f;

        float h0 = hs0p[0];
        h0 = (a5 == 1) ? hs0p[1] : h0;
        h0 = (a5 == 2) ? hs0p[2] : h0;
        h0 = (a5 == 3) ? hs0p[3] : h0;
        h0 = (a5 == 4) ? hs0p[4] : h0;
        h0 = (a5 == 5) ? hs0p[5] : h0;

        float hl = fcom_f + h0;
        #pragma unroll
        for (int t = 0; t < 2; ++t) {
            float r32 = relu_(lb2s[t] + ap24 * cw3s[t]);                       // final win3 s2
            float r33 = relu_(lb3s[t] + ap34 * cw3s[t]);                       // final win3 s3
            float r42 = relu_(b4f2[t] + ap24 * cw2s[t] + ap25 * cw3s[t]);      // final win4 s2
            float r43 = relu_(b4f3[t] + ap34 * cw2s[t] + ap35 * cw3s[t]);      // final win4 s3
            hl += r32 * w32s[t] + r33 * w33s[t] + r42 * w42s[t] + r43 * w43s[t];
        }
        #pragma unroll
        for (int off = 32; off > 0; off >>= 1) hl += __shfl_xor(hl, off);
        if (lane == 0) h_lds[wv] = relu_(hl + bias3);
    }
    __syncthreads();
    if (tid < 6) {
        float p = 0.f;
        #pragma unroll
        for (int w = 0; w < 4; ++w) p += lw4[tid * 128 + b * 4 + w] * h_lds[w];
        __hip_atomic_store(&partials[(3 * NBLK + b) * PSTRIDE + tid], p,
                           __ATOMIC_RELAXED, __HIP_MEMORY_SCOPE_AGENT);
    }
    __syncthreads();
    if (tid == 0)
        __hip_atomic_store(&flags[b * FSTRIDE], 4,
                           __ATOMIC_RELEASE, __HIP_MEMORY_SCOPE_AGENT);
    if (b == 0) {
        if (tid < NBLK) {
            while (__hip_atomic_load(&flags[tid * FSTRIDE], __ATOMIC_ACQUIRE,
                                     __HIP_MEMORY_SCOPE_AGENT) < 4)
                __builtin_amdgcn_s_sleep(1);
        }
        __syncthreads();
        if (tid < 192) {                           // j = tid>>5 (0..5), bb = tid&31
            int j = tid >> 5, bb = tid & 31;
            s_red[j * 32 + bb] =
                __hip_atomic_load(&partials[(3 * NBLK + bb) * PSTRIDE + j],
                                  __ATOMIC_RELAXED, __HIP_MEMORY_SCOPE_AGENT);
        }
        __syncthreads();
        if (tid < 6) {
            float p = lb4v[tid];
            #pragma unroll
            for (int bb = 0; bb < NBLK; ++bb) p += s_red[tid * 32 + bb];
            out[tid] = p;
        }
    }
}

extern "C" void kernel_launch(void* const* d_in, const int* in_sizes, int n_in,
                              void* d_out, int out_size, void* d_ws, size_t ws_size,
                              hipStream_t stream) {
    const float* inp    = (const float*)d_in[0];
    const float* conv_w = (const float*)d_in[1];
    const float* conv_b = (const float*)d_in[2];
    const float* w0     = (const float*)d_in[3];
    const float* b0     = (const float*)d_in[4];
    const float* w1     = (const float*)d_in[5];
    const float* b1     = (const float*)d_in[6];
    const float* w2     = (const float*)d_in[7];
    const float* b2     = (const float*)d_in[8];
    const float* w3     = (const float*)d_in[9];
    const float* b3     = (const float*)d_in[10];
    const float* w4     = (const float*)d_in[11];
    const float* b4     = (const float*)d_in[12];

    int*   flags    = (int*)d_ws;                       // 32 flags, 128 B apart
    float* partials = (float*)((char*)d_ws + 8192);     // 4*32 slots * 256 B

    actor_kernel<<<NBLK, TPB, 0, stream>>>(inp, conv_w, conv_b,
                                           w0, b0, w1, b1, w2, b2,
                                           w3, b3, w4, b4,
                                           (float*)d_out, flags, partials);
}